// Round 3
// baseline (205.663 us; speedup 1.0000x reference)
//
#include <hip/hip_runtime.h>

// HyperedgeAggregator: out[s, :] = mean over members i with segment_ids[i]==s
// of node_embeddings[node_indices[i], :].
//
// NUM_NODES=100000, EMBED_DIM=256, NUM_EDGES=16384, TOTAL=524288.
// segment_ids is SORTED. Two-kernel plan:
//   1) seg_bounds_kernel: one pass over seg_ids -> seg_start[NUM_EDGES+1] in d_ws
//   2) hyperedge_agg_kernel: ONE BLOCK (4 waves) per segment, contiguous
//      chunk of members per wave. KEY CHANGE vs prev round: member indices are
//      wave-UNIFORM, so they are read via SCALAR loads (uniform address ->
//      s_load) and row addresses are SGPR-base + lane*16 voffset:
//        - no ds_bpermute (__shfl) on the load critical path
//        - no per-row VALU address math (SALU instead)
//        - unconditional 8-deep float4 register pipeline in the full-batch
//          path -> 8 VMEM loads in flight per wave, waits are vmcnt(7..0).
//      Partials combined via 4KB LDS, wave 0 writes.

#define EMBED_DIM 256
#define NUM_EDGES 16384
#define TOTAL_MEM 524288

__global__ __launch_bounds__(256) void seg_bounds_kernel(
    const int* __restrict__ seg_ids,   // [TOTAL_MEM], sorted ascending
    int*       __restrict__ seg_start) // [NUM_EDGES+1]
{
    const int i = blockIdx.x * blockDim.x + threadIdx.x;
    if (i >= TOTAL_MEM) return;
    const int cur  = seg_ids[i];
    const int prev = (i == 0) ? -1 : seg_ids[i - 1];
    for (int s = prev + 1; s <= cur; ++s) seg_start[s] = i;
    if (i == TOTAL_MEM - 1) {
        for (int s = cur + 1; s <= NUM_EDGES; ++s) seg_start[s] = TOTAL_MEM;
    }
}

__global__ __launch_bounds__(256) void hyperedge_agg_kernel(
    const float* __restrict__ emb,        // [NUM_NODES, EMBED_DIM]
    const int*   __restrict__ node_idx,   // [TOTAL_MEM]
    const int*   __restrict__ seg_start,  // [NUM_EDGES+1]
    float*       __restrict__ out)        // [NUM_EDGES, EMBED_DIM]
{
    __shared__ float4 partial[4][64];     // 4 KB

    const int tid  = threadIdx.x;
    // force wave id into an SGPR so everything derived from it is uniform
    const int wave = __builtin_amdgcn_readfirstlane(tid >> 6);
    const int lane = tid & 63;
    const int seg  = blockIdx.x;

    const int start = seg_start[seg];   // uniform (blockIdx) -> s_load
    const int end   = seg_start[seg + 1];
    const int len   = end - start;

    // contiguous chunk of members per wave
    const int per = (len + 3) >> 2;
    const int ws  = start + wave * per;
    const int we  = min(ws + per, end);

    float4 acc = make_float4(0.f, 0.f, 0.f, 0.f);

    int b = ws;
    // full batches of 8: unconditional -> 8 loads issued back-to-back,
    // all indices scalar (s_load), addresses SGPR-base + lane*16
    for (; b + 8 <= we; b += 8) {
        float4 v[8];
        #pragma unroll
        for (int u = 0; u < 8; ++u) {
            const int n = node_idx[b + u];             // uniform -> s_load
            v[u] = ((const float4*)(emb + (size_t)n * EMBED_DIM))[lane];
        }
        #pragma unroll
        for (int u = 0; u < 8; ++u) {
            acc.x += v[u].x; acc.y += v[u].y;
            acc.z += v[u].z; acc.w += v[u].w;
        }
    }
    // tail batch (m in [0,8))
    {
        const int m = we - b;
        float4 v[8];
        #pragma unroll
        for (int u = 0; u < 8; ++u)
            if (u < m) {
                const int n = node_idx[b + u];         // uniform -> s_load
                v[u] = ((const float4*)(emb + (size_t)n * EMBED_DIM))[lane];
            }
        #pragma unroll
        for (int u = 0; u < 8; ++u)
            if (u < m) {
                acc.x += v[u].x; acc.y += v[u].y;
                acc.z += v[u].z; acc.w += v[u].w;
            }
    }

    partial[wave][lane] = acc;
    __syncthreads();

    if (wave == 0) {
        const float4 a = partial[0][lane];
        const float4 bb = partial[1][lane];
        const float4 c = partial[2][lane];
        const float4 d = partial[3][lane];
        float4 s;
        s.x = (a.x + bb.x) + (c.x + d.x);
        s.y = (a.y + bb.y) + (c.y + d.y);
        s.z = (a.z + bb.z) + (c.z + d.z);
        s.w = (a.w + bb.w) + (c.w + d.w);
        const float cnt = (len > 0) ? (float)len : 1.0f;
        s.x /= cnt; s.y /= cnt; s.z /= cnt; s.w /= cnt;
        ((float4*)(out + (size_t)seg * EMBED_DIM))[lane] = s;
    }
}

// Fallback (no workspace): per-wave binary search.
__global__ __launch_bounds__(256) void hyperedge_agg_bsearch_kernel(
    const float* __restrict__ emb,
    const int*   __restrict__ node_idx,
    const int*   __restrict__ seg_ids,
    float*       __restrict__ out)
{
    const int wave = threadIdx.x >> 6;
    const int lane = threadIdx.x & 63;
    const int seg  = blockIdx.x * 4 + wave;
    if (seg >= NUM_EDGES) return;

    int lo = 0, hi = TOTAL_MEM;
    while (lo < hi) {
        int mid = (lo + hi) >> 1;
        if (seg_ids[mid] < seg) lo = mid + 1; else hi = mid;
    }
    const int start = lo;
    hi = TOTAL_MEM;
    while (lo < hi) {
        int mid = (lo + hi) >> 1;
        if (seg_ids[mid] < seg + 1) lo = mid + 1; else hi = mid;
    }
    const int end = lo;

    float4 acc = make_float4(0.f, 0.f, 0.f, 0.f);
    for (int i = start; i < end; ++i) {
        const int n = node_idx[i];
        float4 v = ((const float4*)(emb + (size_t)n * EMBED_DIM))[lane];
        acc.x += v.x; acc.y += v.y; acc.z += v.z; acc.w += v.w;
    }
    const float cnt = (end > start) ? (float)(end - start) : 1.0f;
    acc.x /= cnt; acc.y /= cnt; acc.z /= cnt; acc.w /= cnt;
    ((float4*)(out + (size_t)seg * EMBED_DIM))[lane] = acc;
}

extern "C" void kernel_launch(void* const* d_in, const int* in_sizes, int n_in,
                              void* d_out, int out_size, void* d_ws, size_t ws_size,
                              hipStream_t stream) {
    const float* emb      = (const float*)d_in[0];
    const int*   node_idx = (const int*)d_in[1];
    const int*   seg_ids  = (const int*)d_in[2];
    float*       out      = (float*)d_out;

    const size_t bounds_bytes = (size_t)(NUM_EDGES + 1) * sizeof(int);
    if (ws_size >= bounds_bytes) {
        int* seg_start = (int*)d_ws;
        seg_bounds_kernel<<<(TOTAL_MEM + 255) / 256, 256, 0, stream>>>(seg_ids, seg_start);
        hyperedge_agg_kernel<<<NUM_EDGES, 256, 0, stream>>>(emb, node_idx, seg_start, out);
    } else {
        hyperedge_agg_bsearch_kernel<<<NUM_EDGES / 4, 256, 0, stream>>>(emb, node_idx, seg_ids, out);
    }
}